// Round 5
// baseline (67.154 us; speedup 1.0000x reference)
//
#include <hip/hip_runtime.h>
#include <hip/hip_bf16.h>

#define N_ROWS 8192
#define DIMS   128

typedef __bf16 bf16x8 __attribute__((ext_vector_type(8)));
typedef float  f32x4  __attribute__((ext_vector_type(4)));

struct alignas(8) B4 { __hip_bfloat16 h0, h1, h2, h3; };

// ---------------------------------------------------------------------------
// prep: 256 blocks; blocks 0..127 -> cluster1 (bf16 copy scaled by -2, row
// sq-norms, per-block partial colsum + colsumsq), 128..255 -> cluster2
// (scale +1, partial colsum). float4 loads, 2 rows per wave-iteration.
// part layout (TRANSPOSED for coalesced final reads):
//   part[sec*16384 + col*128 + blk], sec 0=colsum1, 1=colsumsq1, 2=colsum2
// ---------------------------------------------------------------------------
__global__ __launch_bounds__(256) void prep_k(const float* __restrict__ c1,
                                              const float* __restrict__ c2,
                                              __hip_bfloat16* __restrict__ c1b,
                                              __hip_bfloat16* __restrict__ c2b,
                                              float* __restrict__ sq1,
                                              float* __restrict__ sq2,
                                              float* __restrict__ part) {
    const int tid  = threadIdx.x;
    const int lane = tid & 63;
    const int wave = tid >> 6;
    const int half = lane >> 5;           // 0: even row, 1: odd row
    const int l32  = lane & 31;           // cols 4*l32 .. 4*l32+3
    const int cl   = blockIdx.x >> 7;     // 0 = cluster1, 1 = cluster2
    const int blk  = blockIdx.x & 127;

    const float* __restrict__ src    = cl ? c2 : c1;
    __hip_bfloat16* __restrict__ dst = cl ? c2b : c1b;
    float* __restrict__ sq           = cl ? sq2 : sq1;
    const float scale                = cl ? 1.0f : -2.0f;

    float4 cs = {0.f, 0.f, 0.f, 0.f};
    float4 cq = {0.f, 0.f, 0.f, 0.f};

    #pragma unroll 4
    for (int i = 0; i < 8; ++i) {
        const int row = blk * 64 + wave * 16 + i * 2 + half;
        float4 x = *reinterpret_cast<const float4*>(src + (size_t)row * DIMS + l32 * 4);
        B4 b4{__float2bfloat16(scale * x.x), __float2bfloat16(scale * x.y),
              __float2bfloat16(scale * x.z), __float2bfloat16(scale * x.w)};
        *reinterpret_cast<B4*>(dst + (size_t)row * DIMS + l32 * 4) = b4;
        float s = x.x * x.x + x.y * x.y + x.z * x.z + x.w * x.w;
        #pragma unroll
        for (int m = 16; m; m >>= 1) s += __shfl_xor(s, m);   // within 32-lane half
        if (l32 == 0) sq[row] = s;
        cs.x += x.x; cs.y += x.y; cs.z += x.z; cs.w += x.w;
        cq.x += x.x * x.x; cq.y += x.y * x.y; cq.z += x.z * x.z; cq.w += x.w * x.w;
    }

    // combine halves (same columns in both halves)
    cs.x += __shfl_xor(cs.x, 32); cs.y += __shfl_xor(cs.y, 32);
    cs.z += __shfl_xor(cs.z, 32); cs.w += __shfl_xor(cs.w, 32);
    cq.x += __shfl_xor(cq.x, 32); cq.y += __shfl_xor(cq.y, 32);
    cq.z += __shfl_xor(cq.z, 32); cq.w += __shfl_xor(cq.w, 32);

    __shared__ float4 lds4[4][32];
    lds4[wave][l32] = cs;
    __syncthreads();
    if (tid < 32) {
        float4 a = lds4[0][tid], b = lds4[1][tid], c = lds4[2][tid], d = lds4[3][tid];
        float4 t = {a.x + b.x + c.x + d.x, a.y + b.y + c.y + d.y,
                    a.z + b.z + c.z + d.z, a.w + b.w + c.w + d.w};
        const int base = cl ? 32768 : 0;
        part[base + (4 * tid + 0) * 128 + blk] = t.x;
        part[base + (4 * tid + 1) * 128 + blk] = t.y;
        part[base + (4 * tid + 2) * 128 + blk] = t.z;
        part[base + (4 * tid + 3) * 128 + blk] = t.w;
    }
    __syncthreads();
    lds4[wave][l32] = cq;
    __syncthreads();
    if (tid < 32 && cl == 0) {
        float4 a = lds4[0][tid], b = lds4[1][tid], c = lds4[2][tid], d = lds4[3][tid];
        float4 t = {a.x + b.x + c.x + d.x, a.y + b.y + c.y + d.y,
                    a.z + b.z + c.z + d.z, a.w + b.w + c.w + d.w};
        part[16384 + (4 * tid + 0) * 128 + blk] = t.x;
        part[16384 + (4 * tid + 1) * 128 + blk] = t.y;
        part[16384 + (4 * tid + 2) * 128 + blk] = t.z;
        part[16384 + (4 * tid + 3) * 128 + blk] = t.w;
    }
}

// ---------------------------------------------------------------------------
// dist: grid 32 row-blocks x 32 col-chunks (1024 blocks, 4/CU at
// launch_bounds(256,4) -> 16 waves/CU for latency hiding). Wave owns only
// 64 rows: a[4][4] = 64 VGPRs, total demand ~125 -> fits the 128-VGPR cap,
// so the allocator has no reason to remat OR spill A (the r2-r4 disease).
// No atomics: per-(row,cb) partial mins stored to pmin[row][32].
// C-in = sq2[col] so the MFMA chain yields sq2 - 2*c1.c2 (c1b pre-scaled
// by -2); epilogue = fmin. sq1 added in reduce_k.
// MFMA 16x16x32 bf16 layouts (validated: absmax 0.0):
//   A: row = lane&15, k = (lane>>4)*8 + j
//   B: col = lane&15, k = (lane>>4)*8 + j
//   D: col = lane&15, row = (lane>>4)*4 + r
// ---------------------------------------------------------------------------
__global__ __launch_bounds__(256, 4) void dist_k(const __hip_bfloat16* __restrict__ c1b,
                                                 const __hip_bfloat16* __restrict__ c2b,
                                                 const float* __restrict__ sq2,
                                                 float* __restrict__ pmin) {
    const int lane = threadIdx.x & 63;
    const int wave = threadIdx.x >> 6;
    const int lo = lane & 15;
    const int hi = lane >> 4;
    const int rb = blockIdx.x >> 5;     // 0..31 : 256-row block
    const int cb = blockIdx.x & 31;     // 0..31 : 256-col chunk
    const int row0 = rb * 256 + wave * 64;
    const int col0 = cb * 256;

    // A fragments: 4 row-subtiles x 4 k-steps = 64 VGPRs, loaded once.
    uint4 a_u[4][4];
    #pragma unroll
    for (int rt = 0; rt < 4; ++rt)
        #pragma unroll
        for (int ks = 0; ks < 4; ++ks)
            a_u[rt][ks] = *reinterpret_cast<const uint4*>(
                c1b + (size_t)(row0 + rt * 16 + lo) * DIMS + ks * 32 + hi * 8);

    // Pin: values become asm outputs -> no rematerialization from memory.
    #pragma unroll
    for (int rt = 0; rt < 4; ++rt)
        #pragma unroll
        for (int ks = 0; ks < 4; ++ks)
            asm volatile("" : "+v"(a_u[rt][ks].x), "+v"(a_u[rt][ks].y),
                              "+v"(a_u[rt][ks].z), "+v"(a_u[rt][ks].w));

    float rmin[4][4];
    #pragma unroll
    for (int rt = 0; rt < 4; ++rt)
        #pragma unroll
        for (int r = 0; r < 4; ++r)
            rmin[rt][r] = __builtin_inff();

    for (int ct = 0; ct < 16; ++ct) {
        const int J = col0 + ct * 16 + lo;
        const float t = sq2[J];
        bf16x8 b[4];
        #pragma unroll
        for (int ks = 0; ks < 4; ++ks)
            b[ks] = *reinterpret_cast<const bf16x8*>(
                c2b + (size_t)J * DIMS + ks * 32 + hi * 8);

        #pragma unroll
        for (int rt = 0; rt < 4; ++rt) {
            f32x4 acc = {t, t, t, t};          // C-in = sq2[col]
            #pragma unroll
            for (int ks = 0; ks < 4; ++ks)
                acc = __builtin_amdgcn_mfma_f32_16x16x32_bf16(
                    __builtin_bit_cast(bf16x8, a_u[rt][ks]), b[ks], acc, 0, 0, 0);
            #pragma unroll
            for (int r = 0; r < 4; ++r)
                rmin[rt][r] = fminf(rmin[rt][r], acc[r]);
        }
    }

    // min across the 16 lanes sharing an output row
    #pragma unroll
    for (int rt = 0; rt < 4; ++rt)
        #pragma unroll
        for (int r = 0; r < 4; ++r) {
            float v = rmin[rt][r];
            v = fminf(v, __shfl_xor(v, 1));
            v = fminf(v, __shfl_xor(v, 2));
            v = fminf(v, __shfl_xor(v, 4));
            v = fminf(v, __shfl_xor(v, 8));
            rmin[rt][r] = v;
        }

    if (lo == 0) {
        #pragma unroll
        for (int rt = 0; rt < 4; ++rt)
            #pragma unroll
            for (int r = 0; r < 4; ++r) {
                int row = row0 + rt * 16 + hi * 4 + r;
                pmin[(size_t)row * 32 + cb] = rmin[rt][r];
            }
    }
}

// ---------------------------------------------------------------------------
// reduce: 32 blocks x 256 threads; thread = one row. Coalesced read of the
// row's 32 partial mins (8 float4), fold min + sq1, block-sum -> rpart[32].
// ---------------------------------------------------------------------------
__global__ __launch_bounds__(256) void reduce_k(const float* __restrict__ pmin,
                                                const float* __restrict__ sq1,
                                                float* __restrict__ rpart) {
    __shared__ float red[256];
    const int tid = threadIdx.x;
    const int row = blockIdx.x * 256 + tid;

    const float4* p = reinterpret_cast<const float4*>(pmin + (size_t)row * 32);
    float4 m4 = p[0];
    #pragma unroll
    for (int i = 1; i < 8; ++i) {
        float4 v = p[i];
        m4.x = fminf(m4.x, v.x); m4.y = fminf(m4.y, v.y);
        m4.z = fminf(m4.z, v.z); m4.w = fminf(m4.w, v.w);
    }
    float m = fminf(fminf(m4.x, m4.y), fminf(m4.z, m4.w)) + sq1[row];

    red[tid] = m;
    __syncthreads();
    for (int off = 128; off; off >>= 1) {
        if (tid < off) red[tid] += red[tid + off];
        __syncthreads();
    }
    if (tid == 0) rpart[blockIdx.x] = red[0];
}

// ---------------------------------------------------------------------------
// finalize: out = (sum rpart)/8192 + mean_c((m1-m2)^2) + mean_c(relu(0.1-var1))
// part[sec][col][blk]: each col-stat job reads 128 consecutive floats.
// ---------------------------------------------------------------------------
__global__ __launch_bounds__(256) void final_k(const float* __restrict__ rpart,
                                               const float* __restrict__ part,
                                               float* __restrict__ out) {
    __shared__ float red[256];
    __shared__ float cs[384];
    const int tid = threadIdx.x;

    // column-stat jobs: j = sec*128 + col, each sums part[j*128 .. j*128+128)
    for (int j = tid; j < 384; j += 256) {
        const float4* p = reinterpret_cast<const float4*>(part + j * 128);
        float4 a = {0.f, 0.f, 0.f, 0.f};
        #pragma unroll 8
        for (int b = 0; b < 32; ++b) {
            float4 v = p[b];
            a.x += v.x; a.y += v.y; a.z += v.z; a.w += v.w;
        }
        cs[j] = a.x + a.y + a.z + a.w;
    }

    float s = (tid < 32) ? rpart[tid] : 0.0f;

    __syncthreads();
    float m = 0.f;
    if (tid < DIMS) {
        const float inv_n = 1.0f / N_ROWS;
        float m1 = cs[tid] * inv_n;
        float vq = cs[128 + tid] * inv_n;
        float m2 = cs[256 + tid] * inv_n;
        float d  = m1 - m2;
        float var = vq - m1 * m1;
        m = d * d + fmaxf(0.1f - var, 0.0f);
    }

    red[tid] = s * (1.0f / N_ROWS) + m * (1.0f / DIMS);
    __syncthreads();
    for (int off = 128; off; off >>= 1) {
        if (tid < off) red[tid] += red[tid + off];
        __syncthreads();
    }
    if (tid == 0) out[0] = red[0];
}

// ---------------------------------------------------------------------------
extern "C" void kernel_launch(void* const* d_in, const int* in_sizes, int n_in,
                              void* d_out, int out_size, void* d_ws, size_t ws_size,
                              hipStream_t stream) {
    (void)in_sizes; (void)n_in; (void)out_size; (void)ws_size;
    const float* c1 = (const float*)d_in[0];
    const float* c2 = (const float*)d_in[1];

    char* ws = (char*)d_ws;
    __hip_bfloat16* c1b = (__hip_bfloat16*)ws;                    // 2 MB
    __hip_bfloat16* c2b = (__hip_bfloat16*)(ws + (1u << 21));     // 2 MB
    float* sq1          = (float*)(ws + (1u << 22));              // 32 KB
    float* sq2          = sq1 + N_ROWS;                           // 32 KB
    float* pmin         = sq2 + N_ROWS;                           // 1 MB
    float* part         = pmin + (size_t)N_ROWS * 32;             // 192 KB
    float* rpart        = part + 3 * 16384;                       // 128 B

    prep_k<<<256, 256, 0, stream>>>(c1, c2, c1b, c2b, sq1, sq2, part);
    dist_k<<<1024, 256, 0, stream>>>(c1b, c2b, sq2, pmin);
    reduce_k<<<32, 256, 0, stream>>>(pmin, sq1, rpart);
    final_k<<<1, 256, 0, stream>>>(rpart, part, (float*)d_out);
}

// Round 6
// 47.582 us; speedup vs baseline: 1.4113x; 1.4113x over previous
//
#include <hip/hip_runtime.h>
#include <hip/hip_bf16.h>

#define N_ROWS 8192
#define DIMS   128

typedef __bf16 bf16x8 __attribute__((ext_vector_type(8)));
typedef float  f32x4  __attribute__((ext_vector_type(4)));

struct alignas(8) B4 { __hip_bfloat16 h0, h1, h2, h3; };

// ---------------------------------------------------------------------------
// prep: 256 blocks; blocks 0..127 -> cluster1 (bf16 copy scaled by -2,
// stored ROW-SWIZZLED: elem ^= (row&7)<<3, i.e. byte ^= (row&7)<<4, so that
// dist_k can stage it LINEARLY with global_load_lds and read bank-conflict-
// free), 128..255 -> cluster2 (scale +1, linear layout — consumed as
// register fragments, never via LDS). Row sq-norms + partial col stats.
// part layout: part[sec*16384 + col*128 + blk], sec 0=cs1, 1=cq1, 2=cs2
// ---------------------------------------------------------------------------
__global__ __launch_bounds__(256) void prep_k(const float* __restrict__ c1,
                                              const float* __restrict__ c2,
                                              __hip_bfloat16* __restrict__ c1b,
                                              __hip_bfloat16* __restrict__ c2b,
                                              float* __restrict__ sq1,
                                              float* __restrict__ sq2,
                                              float* __restrict__ part) {
    const int tid  = threadIdx.x;
    const int lane = tid & 63;
    const int wave = tid >> 6;
    const int half = lane >> 5;           // 0: even row, 1: odd row
    const int l32  = lane & 31;           // cols 4*l32 .. 4*l32+3
    const int cl   = blockIdx.x >> 7;     // 0 = cluster1, 1 = cluster2
    const int blk  = blockIdx.x & 127;

    const float* __restrict__ src    = cl ? c2 : c1;
    __hip_bfloat16* __restrict__ dst = cl ? c2b : c1b;
    float* __restrict__ sq           = cl ? sq2 : sq1;
    const float scale                = cl ? 1.0f : -2.0f;

    float4 cs = {0.f, 0.f, 0.f, 0.f};
    float4 cq = {0.f, 0.f, 0.f, 0.f};

    #pragma unroll 4
    for (int i = 0; i < 8; ++i) {
        const int row = blk * 64 + wave * 16 + i * 2 + half;
        float4 x = *reinterpret_cast<const float4*>(src + (size_t)row * DIMS + l32 * 4);
        B4 b4{__float2bfloat16(scale * x.x), __float2bfloat16(scale * x.y),
              __float2bfloat16(scale * x.z), __float2bfloat16(scale * x.w)};
        // c1b: XOR-swizzle the element offset within the row (16B granules)
        const int eoff = cl ? (l32 * 4) : ((l32 * 4) ^ ((row & 7) << 3));
        *reinterpret_cast<B4*>(dst + (size_t)row * DIMS + eoff) = b4;
        float s = x.x * x.x + x.y * x.y + x.z * x.z + x.w * x.w;
        #pragma unroll
        for (int m = 16; m; m >>= 1) s += __shfl_xor(s, m);   // within 32-lane half
        if (l32 == 0) sq[row] = s;
        cs.x += x.x; cs.y += x.y; cs.z += x.z; cs.w += x.w;
        cq.x += x.x * x.x; cq.y += x.y * x.y; cq.z += x.z * x.z; cq.w += x.w * x.w;
    }

    // combine halves (same columns in both halves)
    cs.x += __shfl_xor(cs.x, 32); cs.y += __shfl_xor(cs.y, 32);
    cs.z += __shfl_xor(cs.z, 32); cs.w += __shfl_xor(cs.w, 32);
    cq.x += __shfl_xor(cq.x, 32); cq.y += __shfl_xor(cq.y, 32);
    cq.z += __shfl_xor(cq.z, 32); cq.w += __shfl_xor(cq.w, 32);

    __shared__ float4 lds4[4][32];
    lds4[wave][l32] = cs;
    __syncthreads();
    if (tid < 32) {
        float4 a = lds4[0][tid], b = lds4[1][tid], c = lds4[2][tid], d = lds4[3][tid];
        float4 t = {a.x + b.x + c.x + d.x, a.y + b.y + c.y + d.y,
                    a.z + b.z + c.z + d.z, a.w + b.w + c.w + d.w};
        const int base = cl ? 32768 : 0;
        part[base + (4 * tid + 0) * 128 + blk] = t.x;
        part[base + (4 * tid + 1) * 128 + blk] = t.y;
        part[base + (4 * tid + 2) * 128 + blk] = t.z;
        part[base + (4 * tid + 3) * 128 + blk] = t.w;
    }
    __syncthreads();
    lds4[wave][l32] = cq;
    __syncthreads();
    if (tid < 32 && cl == 0) {
        float4 a = lds4[0][tid], b = lds4[1][tid], c = lds4[2][tid], d = lds4[3][tid];
        float4 t = {a.x + b.x + c.x + d.x, a.y + b.y + c.y + d.y,
                    a.z + b.z + c.z + d.z, a.w + b.w + c.w + d.w};
        part[16384 + (4 * tid + 0) * 128 + blk] = t.x;
        part[16384 + (4 * tid + 1) * 128 + blk] = t.y;
        part[16384 + (4 * tid + 2) * 128 + blk] = t.z;
        part[16384 + (4 * tid + 3) * 128 + blk] = t.w;
    }
}

// ---------------------------------------------------------------------------
// dist (role-flipped): grid = 32 rowGroups x 16 colGroups = 512 blocks,
// 2 blocks/CU (64 KB LDS each). Wave owns 128 COLUMNS: B fragments
// b_u[8][4] = 128 VGPRs loaded ONCE from L2 (the r1-r5 L2-BW wall is gone).
// A rows [rg*256, +256) staged in LDS (linear copy of pre-swizzled c1b via
// global_load_lds width=16), then streamed as 16 row-tiles: per tile
// 4 swizzled ds_read_b128 feed 32 MFMAs.
// amdgpu_waves_per_eu(2,2): pins 2 waves/SIMD -> 256-VGPR budget, removing
// the allocator's occupancy incentive that caused r5's spill disaster.
// C-in = sq2[col]; epilogue = fmin; sq1 added in reduce_k.
// MFMA 16x16x32 bf16 layouts (validated: absmax 0.0):
//   A: row = lane&15, k = (lane>>4)*8 + j
//   B: col = lane&15, k = (lane>>4)*8 + j
//   D: col = lane&15, row = (lane>>4)*4 + r
// ---------------------------------------------------------------------------
__global__ __attribute__((amdgpu_flat_work_group_size(256, 256),
                          amdgpu_waves_per_eu(2, 2)))
void dist_k(const __hip_bfloat16* __restrict__ c1bs,   // swizzled
            const __hip_bfloat16* __restrict__ c2b,    // linear
            const float* __restrict__ sq2,
            float* __restrict__ pmin) {
    __shared__ uint4 smem4[4096];                      // 64 KB
    char* smem = (char*)smem4;

    const int tid  = threadIdx.x;
    const int lane = tid & 63;
    const int wv   = tid >> 6;
    const int lo = lane & 15;
    const int hi = lane >> 4;
    const int rg = blockIdx.x >> 4;       // 0..31 : 256-row group
    const int cg = blockIdx.x & 15;       // 0..15 : 512-col group
    const int row0 = rg * 256;
    const int col0 = cg * 512 + wv * 128;

    // B fragments: 8 col-tiles x 4 k-steps, loaded once; C-in seeds.
    uint4 b_u[8][4];
    float sq2t[8];
    #pragma unroll
    for (int ct = 0; ct < 8; ++ct) {
        const int J = col0 + ct * 16 + lo;
        sq2t[ct] = sq2[J];
        #pragma unroll
        for (int ks = 0; ks < 4; ++ks)
            b_u[ct][ks] = *reinterpret_cast<const uint4*>(
                c2b + (size_t)J * DIMS + ks * 32 + hi * 8);
    }

    // Stage A rows: linear 64 KB copy (c1bs is pre-swizzled in global).
    {
        const char* gsrc = (const char*)c1bs + (size_t)row0 * 256;
        #pragma unroll
        for (int i = 0; i < 16; ++i) {
            const int off = i * 4096 + wv * 1024;      // wave-uniform LDS dest
            __builtin_amdgcn_global_load_lds(
                (const __attribute__((address_space(1))) unsigned int*)
                    (const void*)(gsrc + off + lane * 16),
                (__attribute__((address_space(3))) unsigned int*)
                    (void*)(smem + off),
                16, 0, 0);
        }
    }

    // Pin B in registers (blocks remat; waves_per_eu blocks spill).
    #pragma unroll
    for (int ct = 0; ct < 8; ++ct)
        #pragma unroll
        for (int ks = 0; ks < 4; ++ks)
            asm volatile("" : "+v"(b_u[ct][ks].x), "+v"(b_u[ct][ks].y),
                              "+v"(b_u[ct][ks].z), "+v"(b_u[ct][ks].w));

    asm volatile("s_waitcnt vmcnt(0)" ::: "memory");
    __syncthreads();

    const int swz = (lo & 7) << 4;
    for (int rt = 0; rt < 16; ++rt) {
        // A fragments for this 16-row tile (swizzled ds_read_b128)
        bf16x8 a[4];
        #pragma unroll
        for (int ks = 0; ks < 4; ++ks) {
            const int boff = (rt * 16 + lo) * 256 + ((ks * 64 + hi * 16) ^ swz);
            a[ks] = *reinterpret_cast<const bf16x8*>(smem + boff);
        }

        float mrow[4] = {__builtin_inff(), __builtin_inff(),
                         __builtin_inff(), __builtin_inff()};

        __builtin_amdgcn_s_setprio(1);
        #pragma unroll
        for (int ct = 0; ct < 8; ++ct) {
            f32x4 acc = {sq2t[ct], sq2t[ct], sq2t[ct], sq2t[ct]};
            #pragma unroll
            for (int ks = 0; ks < 4; ++ks)
                acc = __builtin_amdgcn_mfma_f32_16x16x32_bf16(
                    a[ks], __builtin_bit_cast(bf16x8, b_u[ct][ks]), acc, 0, 0, 0);
            #pragma unroll
            for (int r = 0; r < 4; ++r)
                mrow[r] = fminf(mrow[r], acc[r]);      // sq2 - 2*c1.c2
        }
        __builtin_amdgcn_s_setprio(0);

        // min across the 16 lanes sharing an output row
        #pragma unroll
        for (int r = 0; r < 4; ++r) {
            float v = mrow[r];
            v = fminf(v, __shfl_xor(v, 1));
            v = fminf(v, __shfl_xor(v, 2));
            v = fminf(v, __shfl_xor(v, 4));
            v = fminf(v, __shfl_xor(v, 8));
            mrow[r] = v;
        }
        if (lo == 0) {
            #pragma unroll
            for (int r = 0; r < 4; ++r) {
                const int row = row0 + rt * 16 + hi * 4 + r;
                pmin[(size_t)row * 64 + cg * 4 + wv] = mrow[r];
            }
        }
    }
}

// ---------------------------------------------------------------------------
// reduce: 32 blocks x 256 threads; thread = one row. Coalesced read of the
// row's 64 partial mins (16 float4), fold min + sq1, block-sum -> rpart[32].
// ---------------------------------------------------------------------------
__global__ __launch_bounds__(256) void reduce_k(const float* __restrict__ pmin,
                                                const float* __restrict__ sq1,
                                                float* __restrict__ rpart) {
    __shared__ float red[256];
    const int tid = threadIdx.x;
    const int row = blockIdx.x * 256 + tid;

    const float4* p = reinterpret_cast<const float4*>(pmin + (size_t)row * 64);
    float4 m4 = p[0];
    #pragma unroll
    for (int i = 1; i < 16; ++i) {
        float4 v = p[i];
        m4.x = fminf(m4.x, v.x); m4.y = fminf(m4.y, v.y);
        m4.z = fminf(m4.z, v.z); m4.w = fminf(m4.w, v.w);
    }
    float m = fminf(fminf(m4.x, m4.y), fminf(m4.z, m4.w)) + sq1[row];

    red[tid] = m;
    __syncthreads();
    for (int off = 128; off; off >>= 1) {
        if (tid < off) red[tid] += red[tid + off];
        __syncthreads();
    }
    if (tid == 0) rpart[blockIdx.x] = red[0];
}

// ---------------------------------------------------------------------------
// finalize: out = (sum rpart)/8192 + mean_c((m1-m2)^2) + mean_c(relu(0.1-var1))
// ---------------------------------------------------------------------------
__global__ __launch_bounds__(256) void final_k(const float* __restrict__ rpart,
                                               const float* __restrict__ part,
                                               float* __restrict__ out) {
    __shared__ float red[256];
    __shared__ float cs[384];
    const int tid = threadIdx.x;

    for (int j = tid; j < 384; j += 256) {
        const float4* p = reinterpret_cast<const float4*>(part + j * 128);
        float4 a = {0.f, 0.f, 0.f, 0.f};
        #pragma unroll 8
        for (int b = 0; b < 32; ++b) {
            float4 v = p[b];
            a.x += v.x; a.y += v.y; a.z += v.z; a.w += v.w;
        }
        cs[j] = a.x + a.y + a.z + a.w;
    }

    float s = (tid < 32) ? rpart[tid] : 0.0f;

    __syncthreads();
    float m = 0.f;
    if (tid < DIMS) {
        const float inv_n = 1.0f / N_ROWS;
        float m1 = cs[tid] * inv_n;
        float vq = cs[128 + tid] * inv_n;
        float m2 = cs[256 + tid] * inv_n;
        float d  = m1 - m2;
        float var = vq - m1 * m1;
        m = d * d + fmaxf(0.1f - var, 0.0f);
    }

    red[tid] = s * (1.0f / N_ROWS) + m * (1.0f / DIMS);
    __syncthreads();
    for (int off = 128; off; off >>= 1) {
        if (tid < off) red[tid] += red[tid + off];
        __syncthreads();
    }
    if (tid == 0) out[0] = red[0];
}

// ---------------------------------------------------------------------------
extern "C" void kernel_launch(void* const* d_in, const int* in_sizes, int n_in,
                              void* d_out, int out_size, void* d_ws, size_t ws_size,
                              hipStream_t stream) {
    (void)in_sizes; (void)n_in; (void)out_size; (void)ws_size;
    const float* c1 = (const float*)d_in[0];
    const float* c2 = (const float*)d_in[1];

    char* ws = (char*)d_ws;
    __hip_bfloat16* c1b = (__hip_bfloat16*)ws;                    // 2 MB (swizzled)
    __hip_bfloat16* c2b = (__hip_bfloat16*)(ws + (1u << 21));     // 2 MB
    float* sq1          = (float*)(ws + (1u << 22));              // 32 KB
    float* sq2          = sq1 + N_ROWS;                           // 32 KB
    float* pmin         = sq2 + N_ROWS;                           // 2 MB
    float* part         = pmin + (size_t)N_ROWS * 64;             // 192 KB
    float* rpart        = part + 3 * 16384;                       // 128 B

    prep_k<<<256, 256, 0, stream>>>(c1, c2, c1b, c2b, sq1, sq2, part);
    dist_k<<<512, 256, 0, stream>>>(c1b, c2b, sq2, pmin);
    reduce_k<<<32, 256, 0, stream>>>(pmin, sq1, rpart);
    final_k<<<1, 256, 0, stream>>>(rpart, part, (float*)d_out);
}